// Round 7
// baseline (322.287 us; speedup 1.0000x reference)
//
#include <hip/hip_runtime.h>
#include <hip/hip_bf16.h>

#define D_FEAT 64
#define OVF_CAP 65536
#define W_BITS 8
#define W (1 << W_BITS)          // nodes per bucket
#define PADI 16                  // ints of padding per bucket counter (64B line)

typedef unsigned int uint32;

__device__ inline float blo(uint32 u) { return __uint_as_float(u << 16); }
__device__ inline float bhi(uint32 u) { return __uint_as_float(u & 0xffff0000u); }

// ======================= binned-build path =======================

// coarse histogram onto padded per-bucket counters + fused bf16 cast
__global__ void k_count(const int* __restrict__ col, int* __restrict__ bcnt,
                        const float2* __restrict__ x2, uint32* __restrict__ xb,
                        int nhalf, int E) {
    int t = blockIdx.x * blockDim.x + threadIdx.x;
    if (t < E) atomicAdd(&bcnt[(col[t] >> W_BITS) * PADI], 1);
    const int stride = gridDim.x * blockDim.x;
    for (int j = t; j < nhalf; j += stride) {
        float2 v = x2[j];
        __hip_bfloat16 bx = __float2bfloat16(v.x);
        __hip_bfloat16 by = __float2bfloat16(v.y);
        uint32 ux = *reinterpret_cast<unsigned short*>(&bx);
        uint32 uy = *reinterpret_cast<unsigned short*>(&by);
        xb[j] = ux | (uy << 16);
    }
}

// single-block scan of <=1024 bucket counts -> bstart (exclusive) + cursors
__global__ __launch_bounds__(1024) void k_bscan(const int* __restrict__ bcnt,
                                                int* __restrict__ bstart,
                                                int* __restrict__ bcur, int nb) {
    __shared__ int wsum[16];
    const int tid = threadIdx.x, lane = tid & 63, wv = tid >> 6;
    int v = (tid < nb) ? bcnt[tid * PADI] : 0;
    int s = v;
    #pragma unroll
    for (int off = 1; off < 64; off <<= 1) {
        int t = __shfl_up(s, off, 64);
        if (lane >= off) s += t;
    }
    if (lane == 63) wsum[wv] = s;
    __syncthreads();
    if (wv == 0) {
        int wsv = (lane < 16) ? wsum[lane] : 0;
        int t = wsv;
        #pragma unroll
        for (int off = 1; off < 16; off <<= 1) {
            int u = __shfl_up(t, off, 64);
            if (lane >= off) t += u;
        }
        if (lane < 16) wsum[lane] = t - wsv;
    }
    __syncthreads();
    int excl = wsum[wv] + (s - v);
    if (tid < nb) { bstart[tid] = excl; bcur[tid * PADI] = excl; }
    if (tid == nb - 1) bstart[nb] = excl + v;
}

// append packed (row<<W_BITS | col_local) into the bucket region
__global__ void k_bin(const int* __restrict__ row, const int* __restrict__ col,
                      int* __restrict__ bcur, uint32* __restrict__ binned, int E) {
    int e = blockIdx.x * blockDim.x + threadIdx.x;
    if (e >= E) return;
    int c = col[e];
    uint32 r = (uint32)row[e];
    int b = c >> W_BITS;
    int pos = atomicAdd(&bcur[b * PADI], 1);
    binned[pos] = (r << W_BITS) | (uint32)(c & (W - 1));
}

// one WG per bucket: LDS ranks -> padded slots; fused deg/dis output
__global__ __launch_bounds__(1024) void k_build(const int* __restrict__ bstart,
                                                const uint32* __restrict__ binned,
                                                int* __restrict__ slots,
                                                int* __restrict__ deg,
                                                float* __restrict__ dis,
                                                int2* __restrict__ ovf,
                                                int* __restrict__ ovf_cnt,
                                                int n, int C) {
    __shared__ int cnt[W];
    const int b = blockIdx.x;
    const int s = bstart[b], e = bstart[b + 1];
    if (threadIdx.x < W) cnt[threadIdx.x] = 0;
    __syncthreads();
    const int base_node = b << W_BITS;
    for (int k = s + threadIdx.x; k < e; k += blockDim.x) {
        uint32 pk = binned[k];
        int cl = (int)(pk & (W - 1));
        int r  = (int)(pk >> W_BITS);
        int rk = atomicAdd(&cnt[cl], 1);
        int c  = base_node + cl;
        if (rk < C) {
            slots[(size_t)c * C + rk] = r;
        } else {
            int o = atomicAdd(ovf_cnt, 1);
            if (o < OVF_CAP) ovf[o] = make_int2(r, c);
        }
    }
    __syncthreads();
    int i = base_node + threadIdx.x;
    if (threadIdx.x < W && i < n) {
        int d = cnt[threadIdx.x];
        deg[i] = d;
        dis[i] = (d > 0) ? rsqrtf((float)d) : 0.0f;
    }
}

// ---- gather: one wave per node, 4 edges in parallel, bf16 uint2 loads ----
__global__ void k_gather4(const uint32* __restrict__ xb,
                          const float4* __restrict__ x4,
                          const int* __restrict__ deg,
                          const int* __restrict__ slots,
                          const float* __restrict__ dis,
                          const float* __restrict__ alpha_p,
                          const float* __restrict__ rs_p,
                          float4* __restrict__ out4, int n, int C) {
    int wid = (blockIdx.x * blockDim.x + threadIdx.x) >> 6;
    if (wid >= n) return;
    const int lane = threadIdx.x & 63;
    const int q = lane >> 4;
    const int l = lane & 15;
    int d = deg[wid];
    int e = (d < C) ? d : C;
    const int* sl = slots + (size_t)wid * C;
    float ax = 0.f, ay = 0.f, az = 0.f, aw = 0.f;
    int k = 0;
    for (; k + 8 <= e; k += 8) {
        int s0 = sl[k + q];
        int s1 = sl[k + 4 + q];
        float w0 = dis[s0], w1 = dis[s1];
        uint2 p0 = ((const uint2*)(xb + (size_t)s0 * 32))[l];
        uint2 p1 = ((const uint2*)(xb + (size_t)s1 * 32))[l];
        ax = fmaf(w0, blo(p0.x), ax); ay = fmaf(w0, bhi(p0.x), ay);
        az = fmaf(w0, blo(p0.y), az); aw = fmaf(w0, bhi(p0.y), aw);
        ax = fmaf(w1, blo(p1.x), ax); ay = fmaf(w1, bhi(p1.x), ay);
        az = fmaf(w1, blo(p1.y), az); aw = fmaf(w1, bhi(p1.y), aw);
    }
    for (; k < e; k += 4) {
        int kk = k + q;
        if (kk < e) {
            int s0 = sl[kk];
            float w0 = dis[s0];
            uint2 p0 = ((const uint2*)(xb + (size_t)s0 * 32))[l];
            ax = fmaf(w0, blo(p0.x), ax); ay = fmaf(w0, bhi(p0.x), ay);
            az = fmaf(w0, blo(p0.y), az); aw = fmaf(w0, bhi(p0.y), aw);
        }
    }
    ax += __shfl_down(ax, 32, 64); ay += __shfl_down(ay, 32, 64);
    az += __shfl_down(az, 32, 64); aw += __shfl_down(aw, 32, 64);
    ax += __shfl_down(ax, 16, 64); ay += __shfl_down(ay, 16, 64);
    az += __shfl_down(az, 16, 64); aw += __shfl_down(aw, 16, 64);
    if (q == 0) {
        float adw = (*alpha_p) * dis[wid];
        float rs  = *rs_p;
        float4 xr = x4[(size_t)wid * 16 + l];
        float4 o;
        o.x = fmaf(adw, ax, rs * xr.x);
        o.y = fmaf(adw, ay, rs * xr.y);
        o.z = fmaf(adw, az, rs * xr.z);
        o.w = fmaf(adw, aw, rs * xr.w);
        out4[(size_t)wid * 16 + l] = o;
    }
}

// ---- overflow fix-up (rare): fp32 exact ----
__global__ void k_ovf(const int2* __restrict__ ovf, const int* __restrict__ cnt_p,
                      const float* __restrict__ x, const float* __restrict__ dis,
                      const float* __restrict__ alpha_p, float* __restrict__ out) {
    int cnt = *cnt_p;
    if (cnt > OVF_CAP) cnt = OVF_CAP;
    if (cnt <= 0) return;
    float a = *alpha_p;
    long long total = (long long)cnt * 64;
    long long stride = (long long)gridDim.x * blockDim.x;
    for (long long idx = blockIdx.x * (long long)blockDim.x + threadIdx.x;
         idx < total; idx += stride) {
        int e = (int)(idx >> 6);
        int f = (int)(idx & 63);
        int2 rc = ovf[e];
        float w = a * dis[rc.x] * dis[rc.y];
        atomicAdd(&out[(size_t)rc.y * D_FEAT + f], w * x[(size_t)rc.x * D_FEAT + f]);
    }
}

// ================= round-6 fallback: direct padded-CSR build ================
__global__ void k_prep(const float2* __restrict__ x2, uint32* __restrict__ xb,
                       const int* __restrict__ row, const int* __restrict__ col,
                       int* __restrict__ deg, int* __restrict__ slots,
                       int2* __restrict__ ovf, int* __restrict__ ovf_cnt,
                       int nhalf, int E, int C) {
    int t = blockIdx.x * blockDim.x + threadIdx.x;
    if (t < E) {
        int c = col[t];
        int r = row[t];
        int rk = atomicAdd(&deg[c], 1);
        if (rk < C) {
            slots[(size_t)c * C + rk] = r;
        } else {
            int o = atomicAdd(ovf_cnt, 1);
            if (o < OVF_CAP) ovf[o] = make_int2(r, c);
        }
    }
    const int stride = gridDim.x * blockDim.x;
    for (int j = t; j < nhalf; j += stride) {
        float2 v = x2[j];
        __hip_bfloat16 bx = __float2bfloat16(v.x);
        __hip_bfloat16 by = __float2bfloat16(v.y);
        uint32 ux = *reinterpret_cast<unsigned short*>(&bx);
        uint32 uy = *reinterpret_cast<unsigned short*>(&by);
        xb[j] = ux | (uy << 16);
    }
}
__global__ void k_dis(const int* __restrict__ deg, float* __restrict__ dis, int n) {
    int i = blockIdx.x * blockDim.x + threadIdx.x;
    if (i < n) {
        int d = deg[i];
        dis[i] = (d > 0) ? rsqrtf((float)d) : 0.0f;
    }
}

// ================= last-resort fallback: atomic scatter =====================
__global__ void k_deg_simple(const int* __restrict__ col, int* __restrict__ deg, int E) {
    int e = blockIdx.x * blockDim.x + threadIdx.x;
    if (e < E) atomicAdd(&deg[col[e]], 1);
}
__global__ void k_resid(const float4* __restrict__ x, float4* __restrict__ out,
                        const float* __restrict__ rs_p, int n4) {
    int i = blockIdx.x * blockDim.x + threadIdx.x;
    if (i < n4) {
        float rs = *rs_p;
        float4 v = x[i];
        out[i] = make_float4(rs * v.x, rs * v.y, rs * v.z, rs * v.w);
    }
}
__global__ void k_scatter(const float* __restrict__ x, const int* __restrict__ row,
                          const int* __restrict__ col, const float* __restrict__ dis,
                          const float* __restrict__ alpha_p, float* __restrict__ out, int E) {
    int gid = blockIdx.x * blockDim.x + threadIdx.x;
    int e = gid >> 6, f = gid & 63;
    if (e >= E) return;
    int r = row[e], c = col[e];
    float norm = (*alpha_p) * dis[r] * dis[c];
    atomicAdd(&out[(size_t)c * D_FEAT + f], norm * x[(size_t)r * D_FEAT + f]);
}

static inline char* align_up(char* p, size_t a) {
    return (char*)(((uintptr_t)p + (a - 1)) & ~(uintptr_t)(a - 1));
}

extern "C" void kernel_launch(void* const* d_in, const int* in_sizes, int n_in,
                              void* d_out, int out_size, void* d_ws, size_t ws_size,
                              hipStream_t stream) {
    const float* x         = (const float*)d_in[0];
    const float* alpha     = (const float*)d_in[1];
    const float* res_scale = (const float*)d_in[2];
    const int*   ei        = (const int*)d_in[3];

    const int n = in_sizes[0] / D_FEAT;      // 100000
    const int E = in_sizes[3] / 2;           // 1600000
    const int* row = ei;                     // sources
    const int* col = ei + E;                 // targets

    float* out = (float*)d_out;
    const int nhalf = n * (D_FEAT / 2);
    const int nb = (n + W - 1) >> W_BITS;

    // ---------- try binned path layout ----------
    {
        char* p = (char*)d_ws;
        int2*   ovf     = (int2*)p;               p += (size_t)OVF_CAP * 8;
        int*    deg     = (int*)p;                p += (size_t)n * 4;
        float*  dis     = (float*)p;              p += (size_t)n * 4;
        int*    bstart  = (int*)p;                p += (size_t)(nb + 1) * 4;
        p = align_up(p, 64);
        int*    ovf_cnt = (int*)p;                // ovf_cnt + bcnt contiguous (one memset)
        int*    bcnt    = (int*)(p + 4);          p += 4 + (size_t)nb * PADI * 4;
        int*    bcur    = (int*)p;                p += (size_t)nb * PADI * 4;
        p = align_up(p, 16);
        uint32* xb      = (uint32*)p;             p += (size_t)n * 128;
        uint32* binned  = (uint32*)p;             p += (size_t)E * 4;
        int*    slots   = (int*)p;
        size_t fixed = (size_t)(p - (char*)d_ws);

        int C = 0;
        if (ws_size > fixed) {
            size_t c_avail = (ws_size - fixed) / ((size_t)n * 4);
            C = (c_avail > 64) ? 64 : (int)c_avail;
        }
        bool ok = (C >= 32) && (nb <= 1024) && (n <= (1 << 23));
        if (ok) {
            hipMemsetAsync(ovf_cnt, 0, 4 + (size_t)nb * PADI * 4, stream);
            const int eb = (E + 255) / 256;
            k_count<<<eb, 256, 0, stream>>>(col, bcnt, (const float2*)x, xb, nhalf, E);
            k_bscan<<<1, 1024, 0, stream>>>(bcnt, bstart, bcur, nb);
            k_bin  <<<eb, 256, 0, stream>>>(row, col, bcur, binned, E);
            k_build<<<nb, 1024, 0, stream>>>(bstart, binned, slots, deg, dis,
                                             ovf, ovf_cnt, n, C);
            const long long total = (long long)n * D_FEAT;
            const int blocks = (int)((total + 255) / 256);
            k_gather4<<<blocks, 256, 0, stream>>>(xb, (const float4*)x, deg, slots,
                                                  dis, alpha, res_scale,
                                                  (float4*)out, n, C);
            k_ovf<<<64, 256, 0, stream>>>(ovf, ovf_cnt, x, dis, alpha, out);
            return;
        }
    }

    // ---------- round-6 fallback: direct padded CSR ----------
    {
        const size_t fixed = (size_t)(n + 1) * 4 + (size_t)n * 4 +
                             (size_t)OVF_CAP * 8 + (size_t)n * 128;
        int C = 0;
        if (ws_size > fixed) {
            size_t c_avail = (ws_size - fixed) / ((size_t)n * 4);
            C = (c_avail > 64) ? 64 : (int)c_avail;
        }
        char* wsp = (char*)d_ws;
        int*    deg  = (int*)wsp;      wsp += (size_t)(n + 1) * 4;
        float*  dis  = (float*)wsp;    wsp += (size_t)n * 4;
        int2*   ovf  = (int2*)wsp;     wsp += (size_t)OVF_CAP * 8;
        uint32* xb   = (uint32*)wsp;   wsp += (size_t)n * 128;
        int*    slots = (int*)wsp;
        int*    ovf_cnt = deg + n;

        if (C >= 24) {
            hipMemsetAsync(deg, 0, (size_t)(n + 1) * sizeof(int), stream);
            k_prep<<<(E + 255) / 256, 256, 0, stream>>>(
                (const float2*)x, xb, row, col, deg, slots, ovf, ovf_cnt,
                nhalf, E, C);
            k_dis<<<(n + 255) / 256, 256, 0, stream>>>(deg, dis, n);
            const long long total = (long long)n * D_FEAT;
            const int blocks = (int)((total + 255) / 256);
            k_gather4<<<blocks, 256, 0, stream>>>(xb, (const float4*)x, deg, slots,
                                                  dis, alpha, res_scale,
                                                  (float4*)out, n, C);
            k_ovf<<<64, 256, 0, stream>>>(ovf, ovf_cnt, x, dis, alpha, out);
        } else {
            // ---------- last resort: atomic scatter ----------
            int* deg2 = (int*)d_ws;
            float* dis2 = (float*)((char*)d_ws + (size_t)n * 4);
            hipMemsetAsync(deg2, 0, (size_t)n * sizeof(int), stream);
            k_deg_simple<<<(E + 255) / 256, 256, 0, stream>>>(col, deg2, E);
            k_dis<<<(n + 255) / 256, 256, 0, stream>>>(deg2, dis2, n);
            const int n4 = n * D_FEAT / 4;
            k_resid<<<(n4 + 255) / 256, 256, 0, stream>>>((const float4*)x,
                                                          (float4*)out, res_scale, n4);
            const long long total = (long long)E * D_FEAT;
            const int blocks = (int)((total + 255) / 256);
            k_scatter<<<blocks, 256, 0, stream>>>(x, row, col, dis2, alpha, out, E);
        }
    }
}

// Round 8
// 240.510 us; speedup vs baseline: 1.3400x; 1.3400x over previous
//
#include <hip/hip_runtime.h>
#include <hip/hip_bf16.h>

#define D_FEAT 64
#define OVF_CAP 65536

typedef unsigned int uint32;

__device__ inline float blo(uint32 u) { return __uint_as_float(u << 16); }
__device__ inline float bhi(uint32 u) { return __uint_as_float(u & 0xffff0000u); }
__device__ inline float dinv(int d) { return (d > 0) ? rsqrtf((float)d) : 0.0f; }

// ---- fused: histogram + direct padded-CSR slot write + bf16 cast ----
__global__ void k_prep(const float2* __restrict__ x2, uint32* __restrict__ xb,
                       const int* __restrict__ row, const int* __restrict__ col,
                       int* __restrict__ deg, int* __restrict__ slots,
                       int2* __restrict__ ovf, int* __restrict__ ovf_cnt,
                       int nhalf, int E, int C) {
    int t = blockIdx.x * blockDim.x + threadIdx.x;
    if (t < E) {
        int c = col[t];
        int r = row[t];
        int rk = atomicAdd(&deg[c], 1);
        if (rk < C) {
            slots[(size_t)c * C + rk] = r;
        } else {
            int o = atomicAdd(ovf_cnt, 1);
            if (o < OVF_CAP) ovf[o] = make_int2(r, c);
        }
    }
    const int stride = gridDim.x * blockDim.x;
    for (int j = t; j < nhalf; j += stride) {
        float2 v = x2[j];
        __hip_bfloat16 bx = __float2bfloat16(v.x);
        __hip_bfloat16 by = __float2bfloat16(v.y);
        uint32 ux = *reinterpret_cast<unsigned short*>(&bx);
        uint32 uy = *reinterpret_cast<unsigned short*>(&by);
        xb[j] = ux | (uy << 16);
    }
}

// ---- gather: one wave per node, 4 edges in parallel, 16-edge unroll ----
// lane = (q, l): q = edge slot within quad (lane>>4), l = feat quad (lane&15)
// dis computed on the fly from deg.
__global__ void k_gather4(const uint32* __restrict__ xb,
                          const float4* __restrict__ x4,
                          const int* __restrict__ deg,
                          const int* __restrict__ slots,
                          const float* __restrict__ alpha_p,
                          const float* __restrict__ rs_p,
                          float4* __restrict__ out4, int n, int C) {
    int wid = (blockIdx.x * blockDim.x + threadIdx.x) >> 6;
    if (wid >= n) return;
    const int lane = threadIdx.x & 63;
    const int q = lane >> 4;
    const int l = lane & 15;
    int d = deg[wid];
    int e = (d < C) ? d : C;
    const int* sl = slots + (size_t)wid * C;
    float ax = 0.f, ay = 0.f, az = 0.f, aw = 0.f;
    int k = 0;
    for (; k + 16 <= e; k += 16) {            // 16 edges/iter (4 per quarter)
        int s0 = sl[k + q];
        int s1 = sl[k + 4 + q];
        int s2 = sl[k + 8 + q];
        int s3 = sl[k + 12 + q];
        int d0 = deg[s0], d1 = deg[s1], d2 = deg[s2], d3 = deg[s3];
        uint2 p0 = ((const uint2*)(xb + (size_t)s0 * 32))[l];
        uint2 p1 = ((const uint2*)(xb + (size_t)s1 * 32))[l];
        uint2 p2 = ((const uint2*)(xb + (size_t)s2 * 32))[l];
        uint2 p3 = ((const uint2*)(xb + (size_t)s3 * 32))[l];
        float w0 = dinv(d0), w1 = dinv(d1), w2 = dinv(d2), w3 = dinv(d3);
        ax = fmaf(w0, blo(p0.x), ax); ay = fmaf(w0, bhi(p0.x), ay);
        az = fmaf(w0, blo(p0.y), az); aw = fmaf(w0, bhi(p0.y), aw);
        ax = fmaf(w1, blo(p1.x), ax); ay = fmaf(w1, bhi(p1.x), ay);
        az = fmaf(w1, blo(p1.y), az); aw = fmaf(w1, bhi(p1.y), aw);
        ax = fmaf(w2, blo(p2.x), ax); ay = fmaf(w2, bhi(p2.x), ay);
        az = fmaf(w2, blo(p2.y), az); aw = fmaf(w2, bhi(p2.y), aw);
        ax = fmaf(w3, blo(p3.x), ax); ay = fmaf(w3, bhi(p3.x), ay);
        az = fmaf(w3, blo(p3.y), az); aw = fmaf(w3, bhi(p3.y), aw);
    }
    for (; k < e; k += 4) {                   // leftover edges, 4 at a time
        int kk = k + q;
        if (kk < e) {
            int s0 = sl[kk];
            float w0 = dinv(deg[s0]);
            uint2 p0 = ((const uint2*)(xb + (size_t)s0 * 32))[l];
            ax = fmaf(w0, blo(p0.x), ax); ay = fmaf(w0, bhi(p0.x), ay);
            az = fmaf(w0, blo(p0.y), az); aw = fmaf(w0, bhi(p0.y), aw);
        }
    }
    ax += __shfl_down(ax, 32, 64); ay += __shfl_down(ay, 32, 64);
    az += __shfl_down(az, 32, 64); aw += __shfl_down(aw, 32, 64);
    ax += __shfl_down(ax, 16, 64); ay += __shfl_down(ay, 16, 64);
    az += __shfl_down(az, 16, 64); aw += __shfl_down(aw, 16, 64);
    if (q == 0) {
        float adw = (*alpha_p) * dinv(d);
        float rs  = *rs_p;
        float4 xr = x4[(size_t)wid * 16 + l];
        float4 o;
        o.x = fmaf(adw, ax, rs * xr.x);
        o.y = fmaf(adw, ay, rs * xr.y);
        o.z = fmaf(adw, az, rs * xr.z);
        o.w = fmaf(adw, aw, rs * xr.w);
        out4[(size_t)wid * 16 + l] = o;
    }
}

// ---- overflow fix-up (rare): fp32 exact, dis from deg ----
__global__ void k_ovf(const int2* __restrict__ ovf, const int* __restrict__ cnt_p,
                      const float* __restrict__ x, const int* __restrict__ deg,
                      const float* __restrict__ alpha_p, float* __restrict__ out) {
    int cnt = *cnt_p;
    if (cnt > OVF_CAP) cnt = OVF_CAP;
    if (cnt <= 0) return;
    float a = *alpha_p;
    long long total = (long long)cnt * 64;
    long long stride = (long long)gridDim.x * blockDim.x;
    for (long long idx = blockIdx.x * (long long)blockDim.x + threadIdx.x;
         idx < total; idx += stride) {
        int e = (int)(idx >> 6);
        int f = (int)(idx & 63);
        int2 rc = ovf[e];
        float w = a * dinv(deg[rc.x]) * dinv(deg[rc.y]);
        atomicAdd(&out[(size_t)rc.y * D_FEAT + f], w * x[(size_t)rc.x * D_FEAT + f]);
    }
}

// ================= last-resort fallback: atomic scatter =====================
__global__ void k_deg_simple(const int* __restrict__ col, int* __restrict__ deg, int E) {
    int e = blockIdx.x * blockDim.x + threadIdx.x;
    if (e < E) atomicAdd(&deg[col[e]], 1);
}
__global__ void k_resid(const float4* __restrict__ x, float4* __restrict__ out,
                        const float* __restrict__ rs_p, int n4) {
    int i = blockIdx.x * blockDim.x + threadIdx.x;
    if (i < n4) {
        float rs = *rs_p;
        float4 v = x[i];
        out[i] = make_float4(rs * v.x, rs * v.y, rs * v.z, rs * v.w);
    }
}
__global__ void k_scatter(const float* __restrict__ x, const int* __restrict__ row,
                          const int* __restrict__ col, const int* __restrict__ deg,
                          const float* __restrict__ alpha_p, float* __restrict__ out, int E) {
    int gid = blockIdx.x * blockDim.x + threadIdx.x;
    int e = gid >> 6, f = gid & 63;
    if (e >= E) return;
    int r = row[e], c = col[e];
    float norm = (*alpha_p) * dinv(deg[r]) * dinv(deg[c]);
    atomicAdd(&out[(size_t)c * D_FEAT + f], norm * x[(size_t)r * D_FEAT + f]);
}

extern "C" void kernel_launch(void* const* d_in, const int* in_sizes, int n_in,
                              void* d_out, int out_size, void* d_ws, size_t ws_size,
                              hipStream_t stream) {
    const float* x         = (const float*)d_in[0];
    const float* alpha     = (const float*)d_in[1];
    const float* res_scale = (const float*)d_in[2];
    const int*   ei        = (const int*)d_in[3];

    const int n = in_sizes[0] / D_FEAT;      // 100000
    const int E = in_sizes[3] / 2;           // 1600000
    const int* row = ei;                     // sources
    const int* col = ei + E;                 // targets

    float* out = (float*)d_out;
    const int nhalf = n * (D_FEAT / 2);

    // workspace layout: deg[n] + ovf_cnt (one memset region), ovf, xb, slots
    char* p = (char*)d_ws;
    int*    deg     = (int*)p;                p += (size_t)n * 4;
    int*    ovf_cnt = (int*)p;                p += 4;
    int2*   ovf     = (int2*)p;               p += (size_t)OVF_CAP * 8;
    p = (char*)(((uintptr_t)p + 15) & ~(uintptr_t)15);
    uint32* xb      = (uint32*)p;             p += (size_t)n * 128;
    int*    slots   = (int*)p;
    const size_t fixed = (size_t)(p - (char*)d_ws);

    int C = 0;
    if (ws_size > fixed) {
        size_t c_avail = (ws_size - fixed) / ((size_t)n * 4);
        C = (c_avail > 32) ? 32 : (int)c_avail;   // C=32: slots L2-resident
    }

    if (C >= 16) {
        // ---- padded-CSR path ----
        hipMemsetAsync(deg, 0, (size_t)n * 4 + 4, stream);
        k_prep<<<(E + 255) / 256, 256, 0, stream>>>(
            (const float2*)x, xb, row, col, deg, slots, ovf, ovf_cnt,
            nhalf, E, C);
        const long long total = (long long)n * D_FEAT;
        const int blocks = (int)((total + 255) / 256);
        k_gather4<<<blocks, 256, 0, stream>>>(xb, (const float4*)x, deg, slots,
                                              alpha, res_scale, (float4*)out, n, C);
        k_ovf<<<64, 256, 0, stream>>>(ovf, ovf_cnt, x, deg, alpha, out);
    } else {
        // ---- fallback: atomic scatter (needs only deg) ----
        hipMemsetAsync(deg, 0, (size_t)n * 4, stream);
        k_deg_simple<<<(E + 255) / 256, 256, 0, stream>>>(col, deg, E);
        const int n4 = n * D_FEAT / 4;
        k_resid<<<(n4 + 255) / 256, 256, 0, stream>>>((const float4*)x,
                                                      (float4*)out, res_scale, n4);
        const long long total = (long long)E * D_FEAT;
        const int blocks = (int)((total + 255) / 256);
        k_scatter<<<blocks, 256, 0, stream>>>(x, row, col, deg, alpha, out, E);
    }
}

// Round 9
// 188.329 us; speedup vs baseline: 1.7113x; 1.2771x over previous
//
#include <hip/hip_runtime.h>
#include <hip/hip_bf16.h>

#define D_FEAT 64
#define OVF_CAP 65536
#define EB 4096              // edges per block in the multisplit
#define NBMAX 1024           // max coarse buckets (n <= 256K)

typedef unsigned int uint32;

__device__ inline float blo(uint32 u) { return __uint_as_float(u << 16); }
__device__ inline float bhi(uint32 u) { return __uint_as_float(u & 0xffff0000u); }
__device__ inline float dinv(int d) { return (d > 0) ? rsqrtf((float)d) : 0.0f; }

// ---- phase 1: per-block LDS histogram over coarse buckets + fused bf16 cast ----
__global__ __launch_bounds__(256) void k_hist(const int* __restrict__ col,
                                              int* __restrict__ histT,
                                              const float2* __restrict__ x2,
                                              uint32* __restrict__ xb,
                                              int nhalf, int E, int B, int nb) {
    __shared__ int h[NBMAX];
    for (int i = threadIdx.x; i < nb; i += 256) h[i] = 0;
    __syncthreads();
    const int b = blockIdx.x;
    const int s = b * EB;
    const int e = (s + EB < E) ? s + EB : E;
    for (int i = s + threadIdx.x; i < e; i += 256)
        atomicAdd(&h[col[i] >> 8], 1);
    __syncthreads();
    for (int k = threadIdx.x; k < nb; k += 256)
        histT[(size_t)k * B + b] = h[k];            // bucket-major for the scan
    // fused bf16 cast (bandwidth work, hides behind LDS atomics)
    const int t = b * 256 + threadIdx.x;
    const int stride = B * 256;
    for (int j = t; j < nhalf; j += stride) {
        float2 v = x2[j];
        __hip_bfloat16 bx = __float2bfloat16(v.x);
        __hip_bfloat16 by = __float2bfloat16(v.y);
        uint32 ux = *reinterpret_cast<unsigned short*>(&bx);
        uint32 uy = *reinterpret_cast<unsigned short*>(&by);
        xb[j] = ux | (uy << 16);
    }
}

// ---- phase 2a: per-bucket exclusive scan over blocks (one block per bucket) ----
__global__ __launch_bounds__(512) void k_colscan(int* __restrict__ histT,
                                                 int* __restrict__ total, int B) {
    __shared__ int sh[512];
    const int k = blockIdx.x;
    int v = (threadIdx.x < B) ? histT[(size_t)k * B + threadIdx.x] : 0;
    sh[threadIdx.x] = v;
    __syncthreads();
    for (int off = 1; off < 512; off <<= 1) {
        int t = (threadIdx.x >= off) ? sh[threadIdx.x - off] : 0;
        __syncthreads();
        sh[threadIdx.x] += t;
        __syncthreads();
    }
    int incl = sh[threadIdx.x];
    if (threadIdx.x < B) histT[(size_t)k * B + threadIdx.x] = incl - v;  // exclusive
    if (threadIdx.x == 511) total[k] = incl;
}

// ---- phase 2b: scan bucket totals -> bstart (one block) ----
__global__ __launch_bounds__(1024) void k_tinyscan(const int* __restrict__ total,
                                                   int* __restrict__ bstart, int nb) {
    __shared__ int sh[1024];
    int v = (threadIdx.x < nb) ? total[threadIdx.x] : 0;
    sh[threadIdx.x] = v;
    __syncthreads();
    for (int off = 1; off < 1024; off <<= 1) {
        int t = (threadIdx.x >= off) ? sh[threadIdx.x - off] : 0;
        __syncthreads();
        sh[threadIdx.x] += t;
        __syncthreads();
    }
    if (threadIdx.x < nb) bstart[threadIdx.x] = sh[threadIdx.x] - v;
    if (threadIdx.x == nb - 1) bstart[nb] = sh[threadIdx.x];
}

// ---- phase 3: place edges into bucket segments via LDS cursors (no global atomics) ----
__global__ __launch_bounds__(256) void k_scat3(const int* __restrict__ row,
                                               const int* __restrict__ col,
                                               const int* __restrict__ histT,
                                               const int* __restrict__ bstart,
                                               uint32* __restrict__ binned,
                                               int E, int B, int nb) {
    __shared__ int cur[NBMAX];
    const int b = blockIdx.x;
    for (int k = threadIdx.x; k < nb; k += 256)
        cur[k] = bstart[k] + histT[(size_t)k * B + b];
    __syncthreads();
    const int s = b * EB;
    const int e = (s + EB < E) ? s + EB : E;
    for (int i = s + threadIdx.x; i < e; i += 256) {
        int c = col[i];
        uint32 r = (uint32)row[i];
        int pos = atomicAdd(&cur[c >> 8], 1);       // LDS atomic
        binned[pos] = (r << 8) | (uint32)(c & 255);
    }
}

// ---- phase 4: per-bucket LDS ranks -> padded slots; fused deg output ----
__global__ __launch_bounds__(1024) void k_build(const int* __restrict__ bstart,
                                                const uint32* __restrict__ binned,
                                                int* __restrict__ slots,
                                                int* __restrict__ deg,
                                                int2* __restrict__ ovf,
                                                int* __restrict__ ovf_cnt,
                                                int n, int C) {
    __shared__ int cnt[256];
    const int k = blockIdx.x;
    if (threadIdx.x < 256) cnt[threadIdx.x] = 0;
    __syncthreads();
    const int s = bstart[k], e = bstart[k + 1];
    const int base = k << 8;
    for (int i = s + threadIdx.x; i < e; i += 1024) {
        uint32 pk = binned[i];
        int cl = (int)(pk & 255);
        int r  = (int)(pk >> 8);
        int rk = atomicAdd(&cnt[cl], 1);            // LDS atomic
        int c  = base + cl;
        if (rk < C) {
            slots[(size_t)c * C + rk] = r;          // block-private 32KB window
        } else {
            int o = atomicAdd(ovf_cnt, 1);
            if (o < OVF_CAP) ovf[o] = make_int2(r, c);
        }
    }
    __syncthreads();
    int i = base + threadIdx.x;
    if (threadIdx.x < 256 && i < n) deg[i] = cnt[threadIdx.x];
}

// ---- gather: one wave per node, 4 edges in parallel, 16-edge unroll ----
__global__ void k_gather4(const uint32* __restrict__ xb,
                          const float4* __restrict__ x4,
                          const int* __restrict__ deg,
                          const int* __restrict__ slots,
                          const float* __restrict__ alpha_p,
                          const float* __restrict__ rs_p,
                          float4* __restrict__ out4, int n, int C) {
    int wid = (blockIdx.x * blockDim.x + threadIdx.x) >> 6;
    if (wid >= n) return;
    const int lane = threadIdx.x & 63;
    const int q = lane >> 4;
    const int l = lane & 15;
    int d = deg[wid];
    int e = (d < C) ? d : C;
    const int* sl = slots + (size_t)wid * C;
    float ax = 0.f, ay = 0.f, az = 0.f, aw = 0.f;
    int k = 0;
    for (; k + 16 <= e; k += 16) {
        int s0 = sl[k + q];
        int s1 = sl[k + 4 + q];
        int s2 = sl[k + 8 + q];
        int s3 = sl[k + 12 + q];
        int d0 = deg[s0], d1 = deg[s1], d2 = deg[s2], d3 = deg[s3];
        uint2 p0 = ((const uint2*)(xb + (size_t)s0 * 32))[l];
        uint2 p1 = ((const uint2*)(xb + (size_t)s1 * 32))[l];
        uint2 p2 = ((const uint2*)(xb + (size_t)s2 * 32))[l];
        uint2 p3 = ((const uint2*)(xb + (size_t)s3 * 32))[l];
        float w0 = dinv(d0), w1 = dinv(d1), w2 = dinv(d2), w3 = dinv(d3);
        ax = fmaf(w0, blo(p0.x), ax); ay = fmaf(w0, bhi(p0.x), ay);
        az = fmaf(w0, blo(p0.y), az); aw = fmaf(w0, bhi(p0.y), aw);
        ax = fmaf(w1, blo(p1.x), ax); ay = fmaf(w1, bhi(p1.x), ay);
        az = fmaf(w1, blo(p1.y), az); aw = fmaf(w1, bhi(p1.y), aw);
        ax = fmaf(w2, blo(p2.x), ax); ay = fmaf(w2, bhi(p2.x), ay);
        az = fmaf(w2, blo(p2.y), az); aw = fmaf(w2, bhi(p2.y), aw);
        ax = fmaf(w3, blo(p3.x), ax); ay = fmaf(w3, bhi(p3.x), ay);
        az = fmaf(w3, blo(p3.y), az); aw = fmaf(w3, bhi(p3.y), aw);
    }
    for (; k < e; k += 4) {
        int kk = k + q;
        if (kk < e) {
            int s0 = sl[kk];
            float w0 = dinv(deg[s0]);
            uint2 p0 = ((const uint2*)(xb + (size_t)s0 * 32))[l];
            ax = fmaf(w0, blo(p0.x), ax); ay = fmaf(w0, bhi(p0.x), ay);
            az = fmaf(w0, blo(p0.y), az); aw = fmaf(w0, bhi(p0.y), aw);
        }
    }
    ax += __shfl_down(ax, 32, 64); ay += __shfl_down(ay, 32, 64);
    az += __shfl_down(az, 32, 64); aw += __shfl_down(aw, 32, 64);
    ax += __shfl_down(ax, 16, 64); ay += __shfl_down(ay, 16, 64);
    az += __shfl_down(az, 16, 64); aw += __shfl_down(aw, 16, 64);
    if (q == 0) {
        float adw = (*alpha_p) * dinv(d);
        float rs  = *rs_p;
        float4 xr = x4[(size_t)wid * 16 + l];
        float4 o;
        o.x = fmaf(adw, ax, rs * xr.x);
        o.y = fmaf(adw, ay, rs * xr.y);
        o.z = fmaf(adw, az, rs * xr.z);
        o.w = fmaf(adw, aw, rs * xr.w);
        out4[(size_t)wid * 16 + l] = o;
    }
}

// ---- overflow fix-up (rare): fp32 exact ----
__global__ void k_ovf(const int2* __restrict__ ovf, const int* __restrict__ cnt_p,
                      const float* __restrict__ x, const int* __restrict__ deg,
                      const float* __restrict__ alpha_p, float* __restrict__ out) {
    int cnt = *cnt_p;
    if (cnt > OVF_CAP) cnt = OVF_CAP;
    if (cnt <= 0) return;
    float a = *alpha_p;
    long long total = (long long)cnt * 64;
    long long stride = (long long)gridDim.x * blockDim.x;
    for (long long idx = blockIdx.x * (long long)blockDim.x + threadIdx.x;
         idx < total; idx += stride) {
        int e = (int)(idx >> 6);
        int f = (int)(idx & 63);
        int2 rc = ovf[e];
        float w = a * dinv(deg[rc.x]) * dinv(deg[rc.y]);
        atomicAdd(&out[(size_t)rc.y * D_FEAT + f], w * x[(size_t)rc.x * D_FEAT + f]);
    }
}

// ================= fallback: round-8 direct padded-CSR build =================
__global__ void k_prep(const float2* __restrict__ x2, uint32* __restrict__ xb,
                       const int* __restrict__ row, const int* __restrict__ col,
                       int* __restrict__ deg, int* __restrict__ slots,
                       int2* __restrict__ ovf, int* __restrict__ ovf_cnt,
                       int nhalf, int E, int C) {
    int t = blockIdx.x * blockDim.x + threadIdx.x;
    if (t < E) {
        int c = col[t];
        int r = row[t];
        int rk = atomicAdd(&deg[c], 1);
        if (rk < C) {
            slots[(size_t)c * C + rk] = r;
        } else {
            int o = atomicAdd(ovf_cnt, 1);
            if (o < OVF_CAP) ovf[o] = make_int2(r, c);
        }
    }
    const int stride = gridDim.x * blockDim.x;
    for (int j = t; j < nhalf; j += stride) {
        float2 v = x2[j];
        __hip_bfloat16 bx = __float2bfloat16(v.x);
        __hip_bfloat16 by = __float2bfloat16(v.y);
        uint32 ux = *reinterpret_cast<unsigned short*>(&bx);
        uint32 uy = *reinterpret_cast<unsigned short*>(&by);
        xb[j] = ux | (uy << 16);
    }
}

static inline char* align_up(char* p, size_t a) {
    return (char*)(((uintptr_t)p + (a - 1)) & ~(uintptr_t)(a - 1));
}

extern "C" void kernel_launch(void* const* d_in, const int* in_sizes, int n_in,
                              void* d_out, int out_size, void* d_ws, size_t ws_size,
                              hipStream_t stream) {
    const float* x         = (const float*)d_in[0];
    const float* alpha     = (const float*)d_in[1];
    const float* res_scale = (const float*)d_in[2];
    const int*   ei        = (const int*)d_in[3];

    const int n = in_sizes[0] / D_FEAT;      // 100000
    const int E = in_sizes[3] / 2;           // 1600000
    const int* row = ei;                     // sources
    const int* col = ei + E;                 // targets

    float* out = (float*)d_out;
    const int nhalf = n * (D_FEAT / 2);
    const int nb = (n + 255) >> 8;           // coarse buckets (256 nodes each)
    const int B  = (E + EB - 1) / EB;        // multisplit blocks

    // ---------- multisplit layout ----------
    {
        char* p = (char*)d_ws;
        int*    deg     = (int*)p;            p += (size_t)n * 4;
        int*    ovf_cnt = (int*)p;            p += 4;
        int2*   ovf     = (int2*)p;           p += (size_t)OVF_CAP * 8;
        int*    histT   = (int*)p;            p += (size_t)nb * B * 4;
        int*    total   = (int*)p;            p += (size_t)nb * 4;
        int*    bstart  = (int*)p;            p += (size_t)(nb + 1) * 4;
        p = align_up(p, 16);
        uint32* xb      = (uint32*)p;         p += (size_t)n * 128;
        uint32* binned  = (uint32*)p;         p += (size_t)E * 4;
        int*    slots   = (int*)p;
        const size_t fixed = (size_t)(p - (char*)d_ws);

        int C = 0;
        if (ws_size > fixed) {
            size_t c_avail = (ws_size - fixed) / ((size_t)n * 4);
            C = (c_avail > 32) ? 32 : (int)c_avail;
        }
        const bool ok = (C >= 16) && (nb <= NBMAX) && (B <= 512) &&
                        (n <= (NBMAX << 8));
        if (ok) {
            hipMemsetAsync(ovf_cnt, 0, 4, stream);
            k_hist    <<<B, 256, 0, stream>>>(col, histT, (const float2*)x, xb,
                                              nhalf, E, B, nb);
            k_colscan <<<nb, 512, 0, stream>>>(histT, total, B);
            k_tinyscan<<<1, 1024, 0, stream>>>(total, bstart, nb);
            k_scat3   <<<B, 256, 0, stream>>>(row, col, histT, bstart, binned,
                                              E, B, nb);
            k_build   <<<nb, 1024, 0, stream>>>(bstart, binned, slots, deg,
                                                ovf, ovf_cnt, n, C);
            const long long tt = (long long)n * D_FEAT;
            const int blocks = (int)((tt + 255) / 256);
            k_gather4<<<blocks, 256, 0, stream>>>(xb, (const float4*)x, deg, slots,
                                                  alpha, res_scale, (float4*)out,
                                                  n, C);
            k_ovf<<<64, 256, 0, stream>>>(ovf, ovf_cnt, x, deg, alpha, out);
            return;
        }
    }

    // ---------- fallback: round-8 direct padded CSR ----------
    {
        char* p = (char*)d_ws;
        int*    deg     = (int*)p;            p += (size_t)n * 4;
        int*    ovf_cnt = (int*)p;            p += 4;
        int2*   ovf     = (int2*)p;           p += (size_t)OVF_CAP * 8;
        p = align_up(p, 16);
        uint32* xb      = (uint32*)p;         p += (size_t)n * 128;
        int*    slots   = (int*)p;
        const size_t fixed = (size_t)(p - (char*)d_ws);
        int C = 0;
        if (ws_size > fixed) {
            size_t c_avail = (ws_size - fixed) / ((size_t)n * 4);
            C = (c_avail > 32) ? 32 : (int)c_avail;
        }
        if (C < 1) return;  // ws too small for anything sane
        hipMemsetAsync(deg, 0, (size_t)n * 4 + 4, stream);
        k_prep<<<(E + 255) / 256, 256, 0, stream>>>(
            (const float2*)x, xb, row, col, deg, slots, ovf, ovf_cnt,
            nhalf, E, C);
        const long long tt = (long long)n * D_FEAT;
        const int blocks = (int)((tt + 255) / 256);
        k_gather4<<<blocks, 256, 0, stream>>>(xb, (const float4*)x, deg, slots,
                                              alpha, res_scale, (float4*)out, n, C);
        k_ovf<<<64, 256, 0, stream>>>(ovf, ovf_cnt, x, deg, alpha, out);
    }
}